// Round 4
// baseline (311.503 us; speedup 1.0000x reference)
//
#include <hip/hip_runtime.h>

// Mamba2 quantized decode step, MI355X/gfx950. Round 4.
// int8 quantized operands, mfma_i32_16x16x64_i8 (exact). 7 dispatches.
// R4: shrink k-split partial traffic: KS1 8->2 (P1 17.4->4.4 MB),
//     KS2 16->4 (P2 8.4->2.1 MB). Grid stays >= 1 block/CU for gemm1.

#define B_       64
#define DMODEL   2048
#define DSSM     4096
#define NH       64
#define HD       64
#define DSTATE   128
#define DPROJ    8512
#define XBCLEN   4352   // DSSM + 2*DSTATE
#define KS1      2
#define KS2      4

typedef __attribute__((ext_vector_type(4))) int int4v;

__device__ __forceinline__ float blockMax256(float v, float* sm) {
  #pragma unroll
  for (int off = 32; off > 0; off >>= 1)
    v = fmaxf(v, __shfl_xor(v, off, 64));
  __syncthreads();                       // protect sm from previous use
  if ((threadIdx.x & 63) == 0) sm[threadIdx.x >> 6] = v;
  __syncthreads();
  return fmaxf(fmaxf(sm[0], sm[1]), fmaxf(sm[2], sm[3]));
}

__device__ __forceinline__ float absmax4(float4 v) {
  return fmaxf(fmaxf(fabsf(v.x), fabsf(v.y)), fmaxf(fabsf(v.z), fabsf(v.w)));
}

__device__ __forceinline__ unsigned int pack4(float a, float b, float c, float d,
                                              float rs) {
  int c0 = (int)rintf(a * rs), c1 = (int)rintf(b * rs);
  int c2 = (int)rintf(c * rs), c3 = (int)rintf(d * rs);
  return (unsigned)(c0 & 255) | ((unsigned)(c1 & 255) << 8) |
         ((unsigned)(c2 & 255) << 16) | ((unsigned)(c3 & 255) << 24);
}

// ---------- merged row-wise fake-quant -> int8 levels + scale ----------
template<int COLS>
__device__ __forceinline__ void qrow8(const float* __restrict__ in,
                                      unsigned int* __restrict__ outq,
                                      float* __restrict__ scales, int r, float* sm) {
  constexpr int NV = COLS / 1024;
  const float4* row = (const float4*)(in + (size_t)r * COLS);
  float4 v[NV];
  float m = 0.f;
  #pragma unroll
  for (int i = 0; i < NV; i++) {
    v[i] = row[threadIdx.x + i * 256];
    m = fmaxf(m, absmax4(v[i]));
  }
  float mx = blockMax256(m, sm);
  float s = mx * (1.0f / 127.0f);
  float rs = (s == 0.f) ? 0.f : 127.0f / mx;
  if (s == 0.f) s = 1.f;
  if (threadIdx.x == 0) scales[r] = s;
  unsigned int* orow = outq + (size_t)r * (COLS / 4);
  #pragma unroll
  for (int i = 0; i < NV; i++)
    orow[threadIdx.x + i * 256] = pack4(v[i].x, v[i].y, v[i].z, v[i].w, rs);
}

__global__ __launch_bounds__(256) void kquant_all(
    const float* __restrict__ hidden, const float* __restrict__ W_in,
    const float* __restrict__ W_out,
    unsigned int* __restrict__ xq, unsigned int* __restrict__ winq,
    unsigned int* __restrict__ woq,
    float* __restrict__ sx, float* __restrict__ swin, float* __restrict__ swo) {
  __shared__ float sm[4];
  int bid = blockIdx.x;
  if (bid < DPROJ)                 qrow8<DMODEL>(W_in, winq, swin, bid, sm);
  else if (bid < DPROJ + DMODEL)   qrow8<DSSM>(W_out, woq, swo, bid - DPROJ, sm);
  else                             qrow8<DMODEL>(hidden, xq, sx, bid - DPROJ - DMODEL, sm);
}

// ---------- int8 GEMM: P[split][m][n] = sA[m]*sB[n]*sum_k Aq[m][k]*Bq[n][k] ----------
// M=64. Block = 4 waves, each wave 16 n-cols x 64 m-rows. K=64 per MFMA.
__global__ __launch_bounds__(256) void gemm_q8(
    const char* __restrict__ A, int lda, const float* __restrict__ sA,
    const char* __restrict__ Bq, int ldb, const float* __restrict__ sB,
    float* __restrict__ Pout, int N, int kchunk) {
  int wave = threadIdx.x >> 6;
  int lane = threadIdx.x & 63;
  int l16 = lane & 15, quad = lane >> 4;
  int n0 = blockIdx.x * 64 + wave * 16;
  int k0 = blockIdx.y * kchunk;
  int4v zero = {0, 0, 0, 0};
  int4v acc[4] = {zero, zero, zero, zero};
  const char* brow = Bq + (size_t)(n0 + l16) * ldb + quad * 16;
  const char* arow = A + (size_t)l16 * lda + quad * 16;
  int4v bnext = *(const int4v*)(brow + k0);
  int4v anext[4];
  #pragma unroll
  for (int mt = 0; mt < 4; mt++)
    anext[mt] = *(const int4v*)(arow + (size_t)mt * 16 * lda + k0);
  for (int k = k0; k < k0 + kchunk; k += 64) {
    int4v bcur = bnext;
    int4v acur[4] = {anext[0], anext[1], anext[2], anext[3]};
    if (k + 64 < k0 + kchunk) {
      bnext = *(const int4v*)(brow + k + 64);
      #pragma unroll
      for (int mt = 0; mt < 4; mt++)
        anext[mt] = *(const int4v*)(arow + (size_t)mt * 16 * lda + k + 64);
    }
    #pragma unroll
    for (int mt = 0; mt < 4; mt++)
      acc[mt] = __builtin_amdgcn_mfma_i32_16x16x64_i8(acur[mt], bcur, acc[mt], 0, 0, 0);
  }
  int ncol = n0 + l16;
  float sb = sB[ncol];
  float* pbase = Pout + (size_t)blockIdx.y * 64 * N;
  #pragma unroll
  for (int mt = 0; mt < 4; mt++) {
    #pragma unroll
    for (int r = 0; r < 4; r++) {
      int m = mt * 16 + quad * 4 + r;   // C/D: col=lane&15, row=quad*4+reg (m89)
      pbase[(size_t)m * N + ncol] = (float)acc[mt][r] * sA[m] * sb;
    }
  }
}

// ---------- kmid: reduce GEMM1 partials, split z/xBC/dt, quant xBC, coefs ----------
__global__ __launch_bounds__(256) void kmid(
    const float* __restrict__ P1, const float* __restrict__ dt_bias,
    const float* __restrict__ A_log,
    float* __restrict__ zbuf, float* __restrict__ xbcq, float* __restrict__ coefs) {
  __shared__ float sm[4];
  __shared__ float dts[NH];
  __shared__ float sbc;
  int b = blockIdx.x, t = threadIdx.x;
  float4 v[9];
  float m = 0.f;
  #pragma unroll
  for (int i = 0; i < 9; i++) {
    int idx = t + i * 256;                   // float4 index within 2128-wide row
    if (idx < 2128) {
      const float4* p0 = (const float4*)P1 + (size_t)b * 2128 + idx;
      float4 a = p0[0];
      #pragma unroll
      for (int s = 1; s < KS1; s++) {
        float4 q = p0[(size_t)s * 64 * 2128];
        a.x += q.x; a.y += q.y; a.z += q.z; a.w += q.w;
      }
      v[i] = a;
      if (idx >= 1024 && idx < 2112) m = fmaxf(m, absmax4(a));
      if (idx >= 2112) {                      // dt segment: t in [64,80)
        dts[(t - 64) * 4 + 0] = a.x;
        dts[(t - 64) * 4 + 1] = a.y;
        dts[(t - 64) * 4 + 2] = a.z;
        dts[(t - 64) * 4 + 3] = a.w;
      }
    }
  }
  float mx = blockMax256(m, sm);             // barrier also publishes dts[]
  float s = mx * (1.0f / 127.0f);
  float rs = (s == 0.f) ? 0.f : 127.0f / mx;
  if (s == 0.f) s = 1.f;
  float4 q8 = {0.f, 0.f, 0.f, 0.f};          // quantized i==8 f4 (B/C), t<64
  #pragma unroll
  for (int i = 0; i < 9; i++) {
    int idx = t + i * 256;
    if (idx < 1024) {
      *((float4*)(zbuf + (size_t)b * DSSM) + idx) = v[i];
    } else if (idx < 2112) {
      float4 q;
      q.x = rintf(v[i].x * rs) * s;
      q.y = rintf(v[i].y * rs) * s;
      q.z = rintf(v[i].z * rs) * s;
      q.w = rintf(v[i].w * rs) * s;
      if (i == 8) q8 = q;
      *((float4*)(xbcq + (size_t)b * XBCLEN) + (idx - 1024)) = q;
    }
  }
  // B.C from quantized values: lanes 0..31 hold B f4s, 32..63 hold C f4s (wave 0)
  float4 oth;
  oth.x = __shfl(q8.x, (t & 63) ^ 32, 64);
  oth.y = __shfl(q8.y, (t & 63) ^ 32, 64);
  oth.z = __shfl(q8.z, (t & 63) ^ 32, 64);
  oth.w = __shfl(q8.w, (t & 63) ^ 32, 64);
  float p = 0.f;
  if (t < 32) p = q8.x * oth.x + q8.y * oth.y + q8.z * oth.z + q8.w * oth.w;
  #pragma unroll
  for (int off = 1; off < 32; off <<= 1) p += __shfl_xor(p, off, 64);
  if (t == 0) sbc = p;
  __syncthreads();
  if (t < NH) {
    float dtv = dts[t] + dt_bias[t];
    if (dtv < -2.f) dtv = 0.f;
    else if (dtv <= 2.f)
      dtv = 0.6931471805599453f + 0.5f * dtv + dtv * dtv * (1.f / 8.f)
            + dtv * dtv * dtv * (1.f / 48.f);
    float A = -expf(A_log[t]);
    float dA = fmaxf(dtv * A, -10000.f);
    float e = 1.f + dA + dA * dA * (1.f / 2.f) + dA * dA * dA * (1.f / 6.f)
              + dA * dA * dA * dA * (1.f / 24.f)
              + dA * dA * dA * dA * dA * (1.f / 120.f);
    e = fminf(fmaxf(e, 0.f), 1.f);
    coefs[((size_t)b * NH + t) * 2 + 0] = e;           // sc
    coefs[((size_t)b * NH + t) * 2 + 1] = dtv * sbc;   // dt*(B.C)
  }
}

// ---------- SSM contraction: block per (b,h); fully contiguous loads ----------
__global__ __launch_bounds__(256) void ky(const float* __restrict__ state,
                                          const float* __restrict__ xbcq,
                                          const float* __restrict__ coefs,
                                          float* __restrict__ yraw) {
  int h = blockIdx.x, b = blockIdx.y, t = threadIdx.x;
  const float* xrow = xbcq + (size_t)b * XBCLEN;
  const float* Cv = xrow + DSSM + DSTATE;
  float4 c4 = *(const float4*)(Cv + (t & 31) * 4);
  float2 cf = *(const float2*)(coefs + ((size_t)b * NH + h) * 2);  // {sc, coef}
  const float4* st = (const float4*)(state + ((size_t)b * NH + h) * (HD * DSTATE));
  #pragma unroll
  for (int j = 0; j < 8; j++) {
    float4 s4 = st[j * 256 + t];             // f4 idx i: row=i>>5, n=(i&31)*4
    float acc = s4.x * c4.x + s4.y * c4.y + s4.z * c4.z + s4.w * c4.w;
    #pragma unroll
    for (int off = 1; off < 32; off <<= 1) acc += __shfl_xor(acc, off, 64);
    if ((t & 31) == 0) {
      int r = j * 8 + (t >> 5);
      int d = h * HD + r;
      yraw[(size_t)b * DSSM + d] = cf.x * acc + cf.y * xrow[d];
    }
  }
}

// ---------- epilogue: fq(y) -> +D*x -> *relu(z) -> fq -> int8 levels ----------
__global__ __launch_bounds__(256) void kepi(const float* __restrict__ yraw,
                                            const float* __restrict__ zbuf,
                                            const float* __restrict__ xbcq,
                                            const float* __restrict__ Dv,
                                            unsigned int* __restrict__ q3,
                                            float* __restrict__ sy) {
  __shared__ float sm[4];
  int b = blockIdx.x, t = threadIdx.x;
  const float* yrow = yraw + (size_t)b * DSSM;
  float4 yv[4];
  float m = 0.f;
  #pragma unroll
  for (int i = 0; i < 4; i++) {
    yv[i] = *(const float4*)(yrow + t * 4 + i * 1024);
    m = fmaxf(m, absmax4(yv[i]));
  }
  float mx1 = blockMax256(m, sm);
  float s1 = mx1 * (1.0f / 127.0f);
  float rs1 = (s1 == 0.f) ? 0.f : 127.0f / mx1;
  if (s1 == 0.f) s1 = 1.f;
  float4 y3[4];
  float m2 = 0.f;
  #pragma unroll
  for (int i = 0; i < 4; i++) {
    int idx = t * 4 + i * 1024;
    float4 x4 = *(const float4*)(xbcq + (size_t)b * XBCLEN + idx);
    float4 z4 = *(const float4*)(zbuf + (size_t)b * DSSM + idx);
    float4 d4 = *(const float4*)(Dv + idx);
    float4 r;
    r.x = (rintf(yv[i].x * rs1) * s1 + d4.x * x4.x) * fmaxf(z4.x, 0.f);
    r.y = (rintf(yv[i].y * rs1) * s1 + d4.y * x4.y) * fmaxf(z4.y, 0.f);
    r.z = (rintf(yv[i].z * rs1) * s1 + d4.z * x4.z) * fmaxf(z4.z, 0.f);
    r.w = (rintf(yv[i].w * rs1) * s1 + d4.w * x4.w) * fmaxf(z4.w, 0.f);
    y3[i] = r;
    m2 = fmaxf(m2, absmax4(r));
  }
  float mx3 = blockMax256(m2, sm);
  float s3 = mx3 * (1.0f / 127.0f);
  float rs3 = (s3 == 0.f) ? 0.f : 127.0f / mx3;
  if (s3 == 0.f) s3 = 1.f;
  if (t == 0) sy[b] = s3;
  unsigned int* orow = q3 + (size_t)b * (DSSM / 4);
  #pragma unroll
  for (int i = 0; i < 4; i++)
    orow[t + i * 256] = pack4(y3[i].x, y3[i].y, y3[i].z, y3[i].w, rs3);
}

// ---------- reduce GEMM2 partials -> out ----------
__global__ __launch_bounds__(256) void kout(const float* __restrict__ P2,
                                            float* __restrict__ out) {
  int idx = blockIdx.x * 256 + threadIdx.x;   // f4 index over 64*2048/4 = 32768
  const float4* p = (const float4*)P2;
  float4 s = p[idx];
  #pragma unroll
  for (int i = 1; i < KS2; i++) {
    float4 a = p[(size_t)i * 32768 + idx];
    s.x += a.x; s.y += a.y; s.z += a.z; s.w += a.w;
  }
  ((float4*)out)[idx] = s;
}

extern "C" void kernel_launch(void* const* d_in, const int* in_sizes, int n_in,
                              void* d_out, int out_size, void* d_ws, size_t ws_size,
                              hipStream_t stream) {
  const float* hidden  = (const float*)d_in[0];
  const float* ssm     = (const float*)d_in[1];
  const float* W_in    = (const float*)d_in[2];
  const float* dt_bias = (const float*)d_in[3];
  const float* A_log   = (const float*)d_in[4];
  const float* Dv      = (const float*)d_in[5];
  const float* W_out   = (const float*)d_in[6];
  float* out = (float*)d_out;

  char* p = (char*)d_ws;
  auto alloc = [&](size_t bytes) {
    char* r = p;
    p += (bytes + 255) & ~(size_t)255;
    return r;
  };
  unsigned int* xq   = (unsigned int*)alloc((size_t)B_ * DMODEL);
  unsigned int* winq = (unsigned int*)alloc((size_t)DPROJ * DMODEL);
  unsigned int* woq  = (unsigned int*)alloc((size_t)DMODEL * DSSM);
  unsigned int* q3   = (unsigned int*)alloc((size_t)B_ * DSSM);
  float* sx    = (float*)alloc(B_ * 4);
  float* swin  = (float*)alloc(DPROJ * 4);
  float* swo   = (float*)alloc(DMODEL * 4);
  float* sy    = (float*)alloc(B_ * 4);
  float* P1    = (float*)alloc((size_t)KS1 * B_ * DPROJ * 4);   // 4.4 MB
  float* P2    = (float*)alloc((size_t)KS2 * B_ * DMODEL * 4);  // 2.1 MB
  float* zbuf  = (float*)alloc((size_t)B_ * DSSM * 4);
  float* xbcq  = (float*)alloc((size_t)B_ * XBCLEN * 4);
  float* coefs = (float*)alloc((size_t)B_ * NH * 2 * 4);
  float* yraw  = (float*)alloc((size_t)B_ * DSSM * 4);

  kquant_all<<<DPROJ + DMODEL + B_, 256, 0, stream>>>(hidden, W_in, W_out,
                                                      xq, winq, woq, sx, swin, swo);
  gemm_q8<<<dim3(DPROJ / 64, KS1), 256, 0, stream>>>((const char*)xq, DMODEL, sx,
                                                     (const char*)winq, DMODEL, swin,
                                                     P1, DPROJ, DMODEL / KS1);
  kmid<<<B_, 256, 0, stream>>>(P1, dt_bias, A_log, zbuf, xbcq, coefs);
  ky<<<dim3(NH, B_), 256, 0, stream>>>(ssm, xbcq, coefs, yraw);
  kepi<<<B_, 256, 0, stream>>>(yraw, zbuf, xbcq, Dv, q3, sy);
  gemm_q8<<<dim3(DMODEL / 64, KS2), 256, 0, stream>>>((const char*)q3, DSSM, sy,
                                                      (const char*)woq, DSSM, swo,
                                                      P2, DMODEL, DSSM / KS2);
  kout<<<DMODEL / 16, 256, 0, stream>>>(P2, out);
}

// Round 5
// 307.807 us; speedup vs baseline: 1.0120x; 1.0120x over previous
//
#include <hip/hip_runtime.h>

// Mamba2 quantized decode step, MI355X/gfx950. Round 5.
// Fused quant+GEMM: weight rows are read fp32 ONCE, row-max'd + int8-quantized
// in-register/LDS, then MFMA'd against L2-hot quantized activations.
// 6 dispatches: quantx -> fgemm1 -> kmid -> ky -> kepi -> fgemm2(writes out).

#define B_       64
#define DMODEL   2048
#define DSSM     4096
#define NH       64
#define HD       64
#define DSTATE   128
#define DPROJ    8512
#define XBCLEN   4352   // DSSM + 2*DSTATE
#define KS1      1      // fgemm1 accumulates full K in-block (int32, exact)

typedef __attribute__((ext_vector_type(4))) int int4v;

__device__ __forceinline__ float blockMax256(float v, float* sm) {
  #pragma unroll
  for (int off = 32; off > 0; off >>= 1)
    v = fmaxf(v, __shfl_xor(v, off, 64));
  __syncthreads();
  if ((threadIdx.x & 63) == 0) sm[threadIdx.x >> 6] = v;
  __syncthreads();
  return fmaxf(fmaxf(sm[0], sm[1]), fmaxf(sm[2], sm[3]));
}

__device__ __forceinline__ float absmax4(float4 v) {
  return fmaxf(fmaxf(fabsf(v.x), fabsf(v.y)), fmaxf(fabsf(v.z), fabsf(v.w)));
}

__device__ __forceinline__ unsigned int pack4(float a, float b, float c, float d,
                                              float rs) {
  int c0 = (int)rintf(a * rs), c1 = (int)rintf(b * rs);
  int c2 = (int)rintf(c * rs), c3 = (int)rintf(d * rs);
  return (unsigned)(c0 & 255) | ((unsigned)(c1 & 255) << 8) |
         ((unsigned)(c2 & 255) << 16) | ((unsigned)(c3 & 255) << 24);
}

// ---------- quantize hidden (64 rows x 2048) -> int8 + scale ----------
__global__ __launch_bounds__(256) void quantx(const float* __restrict__ in,
                                              unsigned int* __restrict__ outq,
                                              float* __restrict__ scales) {
  __shared__ float sm[4];
  int r = blockIdx.x;
  const float4* row = (const float4*)(in + (size_t)r * DMODEL);
  float4 v[2];
  float m = 0.f;
  #pragma unroll
  for (int i = 0; i < 2; i++) {
    v[i] = row[threadIdx.x + i * 256];
    m = fmaxf(m, absmax4(v[i]));
  }
  float mx = blockMax256(m, sm);
  float s = mx * (1.0f / 127.0f);
  float rs = (s == 0.f) ? 0.f : 127.0f / mx;
  if (s == 0.f) s = 1.f;
  if (threadIdx.x == 0) scales[r] = s;
  unsigned int* orow = outq + (size_t)r * (DMODEL / 4);
  #pragma unroll
  for (int i = 0; i < 2; i++)
    orow[threadIdx.x + i * 256] = pack4(v[i].x, v[i].y, v[i].z, v[i].w, rs);
}

// ---------- fused quant+GEMM ----------
// Block owns ROWS weight rows (the B operand, n-dim) and all 64 A rows (m).
// Phase 1: per-row absmax (fp32 kept in regs) -> scale. Phase 2: pack int8
// into LDS. Phase 3: mfma_i32_16x16x64_i8, wave w = m-tile w (16 rows).
// C[m][n] = i32acc * sA[m] * sW[n], written straight to Cout (row stride N).
template<int K, int ROWS>
__global__ __launch_bounds__(256) void fgemm(const float* __restrict__ W,
                                             const char* __restrict__ Aq,
                                             const float* __restrict__ sA,
                                             float* __restrict__ Cout, int N) {
  constexpr int NF4 = K / 256;        // float4 per lane per row
  constexpr int RPW = ROWS / 4;       // rows per wave (4 waves)
  constexpr int LSTRIDE = K / 4 + 4;  // uints, padded vs bank conflicts
  __shared__ unsigned int wq[ROWS * LSTRIDE];
  __shared__ float smax[ROWS];
  int t = threadIdx.x, wave = t >> 6, lane = t & 63;
  int n0 = blockIdx.x * ROWS;
  #pragma unroll
  for (int rr = 0; rr < RPW; rr++) {
    int row = wave * RPW + rr;
    const float4* rp = (const float4*)(W + (size_t)(n0 + row) * K);
    float4 v[NF4];
    float m = 0.f;
    #pragma unroll
    for (int c = 0; c < NF4; c++) {
      v[c] = rp[lane + c * 64];
      m = fmaxf(m, absmax4(v[c]));
    }
    #pragma unroll
    for (int off = 32; off > 0; off >>= 1)
      m = fmaxf(m, __shfl_xor(m, off, 64));
    float s = (m == 0.f) ? 1.f : m * (1.0f / 127.0f);
    float rs = (m == 0.f) ? 0.f : 127.0f / m;
    if (lane == 0) smax[row] = s;
    unsigned int* wrow = wq + row * LSTRIDE;
    #pragma unroll
    for (int c = 0; c < NF4; c++)
      wrow[lane + c * 64] = pack4(v[c].x, v[c].y, v[c].z, v[c].w, rs);
  }
  __syncthreads();
  int l16 = lane & 15, quad = lane >> 4;
  int4v acc = {0, 0, 0, 0};
  const char* arow = Aq + (size_t)(wave * 16 + l16) * K + quad * 16;
  const unsigned int* brow = wq + l16 * LSTRIDE + quad * 4;
  for (int k = 0; k < K; k += 256) {          // 4 MFMAs per iter, batched loads
    int4v af[4], bf[4];
    #pragma unroll
    for (int u = 0; u < 4; u++)
      af[u] = *(const int4v*)(arow + k + u * 64);
    #pragma unroll
    for (int u = 0; u < 4; u++) {
      int4v z = {0, 0, 0, 0};
      bf[u] = z;
      if (l16 < ROWS) bf[u] = *(const int4v*)(brow + (k + u * 64) / 4);
    }
    #pragma unroll
    for (int u = 0; u < 4; u++)
      acc = __builtin_amdgcn_mfma_i32_16x16x64_i8(af[u], bf[u], acc, 0, 0, 0);
  }
  if (l16 < ROWS) {
    float sw = smax[l16];
    #pragma unroll
    for (int r = 0; r < 4; r++) {
      int m = wave * 16 + quad * 4 + r;   // C/D: col=lane&15, row=quad*4+reg (m89)
      Cout[(size_t)m * N + n0 + l16] = (float)acc[r] * sA[m] * sw;
    }
  }
}

// ---------- kmid: split z/xBC/dt from zxb, quant xBC, coefs ----------
__global__ __launch_bounds__(256) void kmid(
    const float* __restrict__ P1, const float* __restrict__ dt_bias,
    const float* __restrict__ A_log,
    float* __restrict__ zbuf, float* __restrict__ xbcq, float* __restrict__ coefs) {
  __shared__ float sm[4];
  __shared__ float dts[NH];
  __shared__ float sbc;
  int b = blockIdx.x, t = threadIdx.x;
  float4 v[9];
  float m = 0.f;
  #pragma unroll
  for (int i = 0; i < 9; i++) {
    int idx = t + i * 256;                   // float4 index within 2128-wide row
    if (idx < 2128) {
      const float4* p0 = (const float4*)P1 + (size_t)b * 2128 + idx;
      float4 a = p0[0];
      #pragma unroll
      for (int s = 1; s < KS1; s++) {
        float4 q = p0[(size_t)s * 64 * 2128];
        a.x += q.x; a.y += q.y; a.z += q.z; a.w += q.w;
      }
      v[i] = a;
      if (idx >= 1024 && idx < 2112) m = fmaxf(m, absmax4(a));
      if (idx >= 2112) {                      // dt segment: t in [64,80)
        dts[(t - 64) * 4 + 0] = a.x;
        dts[(t - 64) * 4 + 1] = a.y;
        dts[(t - 64) * 4 + 2] = a.z;
        dts[(t - 64) * 4 + 3] = a.w;
      }
    }
  }
  float mx = blockMax256(m, sm);             // barrier also publishes dts[]
  float s = mx * (1.0f / 127.0f);
  float rs = (s == 0.f) ? 0.f : 127.0f / mx;
  if (s == 0.f) s = 1.f;
  float4 q8 = {0.f, 0.f, 0.f, 0.f};          // quantized i==8 f4 (B/C), t<64
  #pragma unroll
  for (int i = 0; i < 9; i++) {
    int idx = t + i * 256;
    if (idx < 1024) {
      *((float4*)(zbuf + (size_t)b * DSSM) + idx) = v[i];
    } else if (idx < 2112) {
      float4 q;
      q.x = rintf(v[i].x * rs) * s;
      q.y = rintf(v[i].y * rs) * s;
      q.z = rintf(v[i].z * rs) * s;
      q.w = rintf(v[i].w * rs) * s;
      if (i == 8) q8 = q;
      *((float4*)(xbcq + (size_t)b * XBCLEN) + (idx - 1024)) = q;
    }
  }
  // B.C from quantized values: lanes 0..31 hold B f4s, 32..63 hold C f4s (wave 0)
  float4 oth;
  oth.x = __shfl(q8.x, (t & 63) ^ 32, 64);
  oth.y = __shfl(q8.y, (t & 63) ^ 32, 64);
  oth.z = __shfl(q8.z, (t & 63) ^ 32, 64);
  oth.w = __shfl(q8.w, (t & 63) ^ 32, 64);
  float p = 0.f;
  if (t < 32) p = q8.x * oth.x + q8.y * oth.y + q8.z * oth.z + q8.w * oth.w;
  #pragma unroll
  for (int off = 1; off < 32; off <<= 1) p += __shfl_xor(p, off, 64);
  if (t == 0) sbc = p;
  __syncthreads();
  if (t < NH) {
    float dtv = dts[t] + dt_bias[t];
    if (dtv < -2.f) dtv = 0.f;
    else if (dtv <= 2.f)
      dtv = 0.6931471805599453f + 0.5f * dtv + dtv * dtv * (1.f / 8.f)
            + dtv * dtv * dtv * (1.f / 48.f);
    float A = -expf(A_log[t]);
    float dA = fmaxf(dtv * A, -10000.f);
    float e = 1.f + dA + dA * dA * (1.f / 2.f) + dA * dA * dA * (1.f / 6.f)
              + dA * dA * dA * dA * (1.f / 24.f)
              + dA * dA * dA * dA * dA * (1.f / 120.f);
    e = fminf(fmaxf(e, 0.f), 1.f);
    coefs[((size_t)b * NH + t) * 2 + 0] = e;           // sc
    coefs[((size_t)b * NH + t) * 2 + 1] = dtv * sbc;   // dt*(B.C)
  }
}

// ---------- SSM contraction: block per (b,h); fully contiguous loads ----------
__global__ __launch_bounds__(256) void ky(const float* __restrict__ state,
                                          const float* __restrict__ xbcq,
                                          const float* __restrict__ coefs,
                                          float* __restrict__ yraw) {
  int h = blockIdx.x, b = blockIdx.y, t = threadIdx.x;
  const float* xrow = xbcq + (size_t)b * XBCLEN;
  const float* Cv = xrow + DSSM + DSTATE;
  float4 c4 = *(const float4*)(Cv + (t & 31) * 4);
  float2 cf = *(const float2*)(coefs + ((size_t)b * NH + h) * 2);  // {sc, coef}
  const float4* st = (const float4*)(state + ((size_t)b * NH + h) * (HD * DSTATE));
  #pragma unroll
  for (int j = 0; j < 8; j++) {
    float4 s4 = st[j * 256 + t];             // f4 idx i: row=i>>5, n=(i&31)*4
    float acc = s4.x * c4.x + s4.y * c4.y + s4.z * c4.z + s4.w * c4.w;
    #pragma unroll
    for (int off = 1; off < 32; off <<= 1) acc += __shfl_xor(acc, off, 64);
    if ((t & 31) == 0) {
      int r = j * 8 + (t >> 5);
      int d = h * HD + r;
      yraw[(size_t)b * DSSM + d] = cf.x * acc + cf.y * xrow[d];
    }
  }
}

// ---------- epilogue: fq(y) -> +D*x -> *relu(z) -> fq -> int8 levels ----------
__global__ __launch_bounds__(256) void kepi(const float* __restrict__ yraw,
                                            const float* __restrict__ zbuf,
                                            const float* __restrict__ xbcq,
                                            const float* __restrict__ Dv,
                                            unsigned int* __restrict__ q3,
                                            float* __restrict__ sy) {
  __shared__ float sm[4];
  int b = blockIdx.x, t = threadIdx.x;
  const float* yrow = yraw + (size_t)b * DSSM;
  float4 yv[4];
  float m = 0.f;
  #pragma unroll
  for (int i = 0; i < 4; i++) {
    yv[i] = *(const float4*)(yrow + t * 4 + i * 1024);
    m = fmaxf(m, absmax4(yv[i]));
  }
  float mx1 = blockMax256(m, sm);
  float s1 = mx1 * (1.0f / 127.0f);
  float rs1 = (s1 == 0.f) ? 0.f : 127.0f / mx1;
  if (s1 == 0.f) s1 = 1.f;
  float4 y3[4];
  float m2 = 0.f;
  #pragma unroll
  for (int i = 0; i < 4; i++) {
    int idx = t * 4 + i * 1024;
    float4 x4 = *(const float4*)(xbcq + (size_t)b * XBCLEN + idx);
    float4 z4 = *(const float4*)(zbuf + (size_t)b * DSSM + idx);
    float4 d4 = *(const float4*)(Dv + idx);
    float4 r;
    r.x = (rintf(yv[i].x * rs1) * s1 + d4.x * x4.x) * fmaxf(z4.x, 0.f);
    r.y = (rintf(yv[i].y * rs1) * s1 + d4.y * x4.y) * fmaxf(z4.y, 0.f);
    r.z = (rintf(yv[i].z * rs1) * s1 + d4.z * x4.z) * fmaxf(z4.z, 0.f);
    r.w = (rintf(yv[i].w * rs1) * s1 + d4.w * x4.w) * fmaxf(z4.w, 0.f);
    y3[i] = r;
    m2 = fmaxf(m2, absmax4(r));
  }
  float mx3 = blockMax256(m2, sm);
  float s3 = mx3 * (1.0f / 127.0f);
  float rs3 = (s3 == 0.f) ? 0.f : 127.0f / mx3;
  if (s3 == 0.f) s3 = 1.f;
  if (t == 0) sy[b] = s3;
  unsigned int* orow = q3 + (size_t)b * (DSSM / 4);
  #pragma unroll
  for (int i = 0; i < 4; i++)
    orow[t + i * 256] = pack4(y3[i].x, y3[i].y, y3[i].z, y3[i].w, rs3);
}

extern "C" void kernel_launch(void* const* d_in, const int* in_sizes, int n_in,
                              void* d_out, int out_size, void* d_ws, size_t ws_size,
                              hipStream_t stream) {
  const float* hidden  = (const float*)d_in[0];
  const float* ssm     = (const float*)d_in[1];
  const float* W_in    = (const float*)d_in[2];
  const float* dt_bias = (const float*)d_in[3];
  const float* A_log   = (const float*)d_in[4];
  const float* Dv      = (const float*)d_in[5];
  const float* W_out   = (const float*)d_in[6];
  float* out = (float*)d_out;

  char* p = (char*)d_ws;
  auto alloc = [&](size_t bytes) {
    char* r = p;
    p += (bytes + 255) & ~(size_t)255;
    return r;
  };
  unsigned int* xq = (unsigned int*)alloc((size_t)B_ * DMODEL);
  unsigned int* q3 = (unsigned int*)alloc((size_t)B_ * DSSM);
  float* sx    = (float*)alloc(B_ * 4);
  float* sy    = (float*)alloc(B_ * 4);
  float* zxb   = (float*)alloc((size_t)B_ * DPROJ * 4);    // 2.2 MB
  float* zbuf  = (float*)alloc((size_t)B_ * DSSM * 4);
  float* xbcq  = (float*)alloc((size_t)B_ * XBCLEN * 4);
  float* coefs = (float*)alloc((size_t)B_ * NH * 2 * 4);
  float* yraw  = (float*)alloc((size_t)B_ * DSSM * 4);

  quantx<<<B_, 256, 0, stream>>>(hidden, xq, sx);
  fgemm<DMODEL, 16><<<DPROJ / 16, 256, 0, stream>>>(W_in, (const char*)xq, sx,
                                                    zxb, DPROJ);
  kmid<<<B_, 256, 0, stream>>>(zxb, dt_bias, A_log, zbuf, xbcq, coefs);
  ky<<<dim3(NH, B_), 256, 0, stream>>>(ssm, xbcq, coefs, yraw);
  kepi<<<B_, 256, 0, stream>>>(yraw, zbuf, xbcq, Dv, q3, sy);
  fgemm<DSSM, 4><<<DMODEL / 4, 256, 0, stream>>>(W_out, (const char*)q3, sy,
                                                 out, DMODEL);
}